// Round 11
// baseline (328.997 us; speedup 1.0000x reference)
//
#include <hip/hip_runtime.h>
#include <math.h>

#define N_ROWS 32768
#define DIM    1024
#define NE     64
#define KTOP   8

// v12: two-kernel split + 4-way k-split grid.
//
// Evidence: v5/v9/v11 all ~148-161us with every pipe <=40%; v11 proved
// staging latency is NOT the cost (full prefetch = null); occupancy is
// grid+VGPR capped (2 blocks/CU, 16 waves/CU) with identical serial chains.
// Fix = more independent work per CU, not more scheduling:
//   kernel 1 (grid 2048 = 512 rowgroups x 4 k-quarters): v5's proven 8x8
//     register-tile main loop over a 256-k quarter (4 rounds), proven
//     stride-68 reduction, then atomicAdd of the 64x64 partial into out0
//     (logits canvas, zeroed each launch by our memset).
//   kernel 2 (grid 512): v0-proven epilogue verbatim, logits read from out0
//     (read-then-overwrite per row within one wave iteration), esum/ticket
//     loss tail unchanged.
// fp32 atomic reorder perturbs logits ~1e-4 << the ~1e-3 reorder slack the
// passing kernels already exercise. Same-stream kernel ordering handles
// cross-kernel visibility.

extern "C" __global__ void __launch_bounds__(512, 4)
moe_gemm_kernel(const float* __restrict__ x, const float* __restrict__ gw,
                float* __restrict__ logits) {
    __shared__ __align__(16) float smem[8192];   // 32 KB
    float* xt  = smem;          // [8 wid][8 q][64 row] private slices
    float* wt  = smem + 4096;   // [8 wid][8 q][64 e]   private slices
    float* red = smem;          // overlay: [8 wid][544] = wid*544 + rr*68 + e

    const int tid  = threadIdx.x;
    const int lane = tid & 63;
    const int wid  = __builtin_amdgcn_readfirstlane(tid >> 6);   // 0..7
    const int er   = lane >> 3;       // expert-group: experts er*8 + n
    const int rr   = lane & 7;        // row-group:    rows    rr*8 + m
    const int er8  = er * 8;
    const int rr8  = rr * 8;
    const int rg   = blockIdx.x >> 2;         // row-group id
    const int kq   = blockIdx.x & 3;          // k-quarter id
    const int row0 = rg * 64;
    const int kwb  = kq * 256 + wid * 32;     // wave's 32-k slice

    float acc[8][8];
#pragma unroll
    for (int m = 0; m < 8; ++m)
#pragma unroll
        for (int n = 0; n < 8; ++n) acc[m][n] = 0.f;

    // staging: thread (wid,lane) loads x[row0+lane][kwb+rnd*8..+8] and
    // gw[lane][kwb+rnd*8..+8]; writes k-major into its wave's private slices.
    const float* gx   = x  + (size_t)(row0 + lane) * DIM + kwb;
    const float* gwp  = gw + (size_t)lane * DIM + kwb;
    float*       ws_x = xt + wid * 512 + lane;     // + q*64
    float*       ws_w = wt + wid * 512 + lane;
    const float* rd_x = xt + wid * 512 + rr8;      // + q*64
    const float* rd_w = wt + wid * 512 + er8;

#pragma unroll 1
    for (int rnd = 0; rnd < 4; ++rnd) {
        // ---- stage this round (px/pw transient: load -> ds_write, dead) ----
        {
            float px[8], pw[8];
            *(float4*)(px + 0) = *(const float4*)(gx  + rnd * 8 + 0);
            *(float4*)(px + 4) = *(const float4*)(gx  + rnd * 8 + 4);
            *(float4*)(pw + 0) = *(const float4*)(gwp + rnd * 8 + 0);
            *(float4*)(pw + 4) = *(const float4*)(gwp + rnd * 8 + 4);
#pragma unroll
            for (int q = 0; q < 8; ++q) {   // lane-consecutive words: free
                ws_x[q * 64] = px[q];
                ws_w[q * 64] = pw[q];
            }
        }
        // ---- v5-proven q-loop (unroll 1) ----
#pragma unroll 1
        for (int q = 0; q < 8; ++q) {
            float xf[8], wf[8];
            *(float4*)(xf + 0) = *(const float4*)(rd_x + q * 64 + 0);
            *(float4*)(xf + 4) = *(const float4*)(rd_x + q * 64 + 4);
            *(float4*)(wf + 0) = *(const float4*)(rd_w + q * 64 + 0);
            *(float4*)(wf + 4) = *(const float4*)(rd_w + q * 64 + 4);
#pragma unroll
            for (int m = 0; m < 8; ++m)
#pragma unroll
                for (int n = 0; n < 8; ++n)
                    acc[m][n] = fmaf(xf[m], wf[n], acc[m][n]);
        }
    }

    // ---- k-split reduction over the 8 waves (stride-68, proven), then
    //      atomic accumulation of this quarter's partial into logits ----
    __syncthreads();                  // all waves done with xt/wt
#pragma unroll
    for (int s = 0; s < 8; ++s) {     // row = rr*8 + s
        float4 v0 = make_float4(acc[s][0], acc[s][1], acc[s][2], acc[s][3]);
        float4 v1 = make_float4(acc[s][4], acc[s][5], acc[s][6], acc[s][7]);
        *(float4*)(red + wid * 544 + rr * 68 + er8 + 0) = v0;
        *(float4*)(red + wid * 544 + rr * 68 + er8 + 4) = v1;
        __syncthreads();
        {
            const int r2 = tid >> 6, e = tid & 63;
            float t = 0.f;
#pragma unroll
            for (int w = 0; w < 8; ++w) t += red[w * 544 + r2 * 68 + e];
            atomicAdd(&logits[(size_t)(row0 + r2 * 8 + s) * NE + e], t);
        }
        __syncthreads();              // red reuse next s
    }
}

extern "C" __global__ void __launch_bounds__(512, 4)
moe_epi_kernel(const float* __restrict__ nw, const float* __restrict__ noise,
               float* __restrict__ out0, float* __restrict__ out1,
               float* __restrict__ lossp,
               double* __restrict__ esum, int* __restrict__ ticket) {
    __shared__ float red[8 * 64];
    __shared__ int isLast;

    const int tid  = threadIdx.x;
    const int lane = tid & 63;
    const int wid  = __builtin_amdgcn_readfirstlane(tid >> 6);   // 0..7
    const int row0 = blockIdx.x * 64;

    // ---- epilogue: wave handles 8 rows, lane = expert (v0-proven code;
    //      logits read from out0, overwritten after use per-row) ----
    const float nwl = nw[lane];
    float epart = 0.f;

#pragma unroll 1
    for (int i = 0; i < 8; ++i) {
        const int    lrow = wid * 8 + i;
        const size_t grow = (size_t)(row0 + lrow);
        const float  lgv  = out0[grow * NE + lane];   // coalesced 256 B/row

        // dense softmax over 64 experts (load-balance mean term)
        float m = lgv;
#pragma unroll
        for (int off = 32; off; off >>= 1) m = fmaxf(m, __shfl_xor(m, off));
        float p = __expf(lgv - m);
        float s = p;
#pragma unroll
        for (int off = 32; off; off >>= 1) s += __shfl_xor(s, off);
        epart += p / s;

        // noisy logits + iterative top-8 argmax (tie -> lower index)
        const float nz    = noise[grow * NE + lane];
        const float noisy = fmaf(nz, nwl, lgv);
        float cur  = noisy;
        bool  sel  = false;
        float mtop = 0.f;
        int   myid = 0;
#pragma unroll
        for (int j = 0; j < KTOP; ++j) {
            float v = cur; int id = lane;
#pragma unroll
            for (int off = 32; off; off >>= 1) {
                float ov = __shfl_xor(v, off);
                int   oi = __shfl_xor(id, off);
                if (ov > v || (ov == v && oi < id)) { v = ov; id = oi; }
            }
            if (j == 0) mtop = v;
            if (lane == id) { sel = true; cur = -INFINITY; }
            if (lane == j) myid = id;
        }

        float swv  = sel ? __expf(noisy - mtop) : 0.f;
        float ssum = swv;
#pragma unroll
        for (int off = 32; off; off >>= 1) ssum += __shfl_xor(ssum, off);

        out0[grow * NE + lane] = swv / ssum;                // overwrite logits
        if (lane < KTOP) out1[grow * KTOP + lane] = (float)myid;
    }

    // ---- load-balance sums: block partial -> device atomics ----
    __syncthreads();
    red[wid * 64 + lane] = epart;
    __syncthreads();
    if (tid < NE) {
        float t = 0.f;
#pragma unroll
        for (int w = 0; w < 8; ++w) t += red[w * 64 + tid];
        atomicAdd(&esum[tid], (double)t);
        __threadfence();
    }
    __syncthreads();
    if (tid == 0) {
        int t = atomicAdd(ticket, 1);
        isLast = (t == (int)gridDim.x - 1);
        __threadfence();
    }
    __syncthreads();

    // ---- last block computes the scalar loss (f64) ----
    if (isLast && tid < NE) {
        double v = atomicAdd(&esum[tid], 0.0);    // device-scope read
        double mean = v * (1.0 / 32768.0);
        double d  = mean - (1.0 / 64.0);
        double sq = d * d;
#pragma unroll
        for (int off = 32; off; off >>= 1) sq += __shfl_xor(sq, off);
        if (tid == 0) lossp[0] = (float)(sq * (1.0 / 64.0) * 0.01);
    }
}

extern "C" void kernel_launch(void* const* d_in, const int* in_sizes, int n_in,
                              void* d_out, int out_size, void* d_ws, size_t ws_size,
                              hipStream_t stream) {
    const float* x     = (const float*)d_in[0];   // [32768,1024]
    const float* gw    = (const float*)d_in[1];   // [64,1024]
    const float* nw    = (const float*)d_in[2];   // [64]
    const float* noise = (const float*)d_in[3];   // [32768,64]

    float* out0  = (float*)d_out;                       // [32768,64] logits -> gated weights
    float* out1  = out0 + (size_t)N_ROWS * NE;          // [32768,8] ids as f32
    float* lossp = out1 + (size_t)N_ROWS * KTOP;        // scalar loss

    double* esum   = (double*)d_ws;                     // [64]
    int*    ticket = (int*)((char*)d_ws + 512);

    hipMemsetAsync(d_ws, 0, 520, stream);
    hipMemsetAsync(out0, 0, (size_t)N_ROWS * NE * sizeof(float), stream);
    moe_gemm_kernel<<<N_ROWS / 64 * 4, 512, 0, stream>>>(x, gw, out0);
    moe_epi_kernel<<<N_ROWS / 64, 512, 0, stream>>>(nw, noise, out0, out1,
                                                    lossp, esum, ticket);
}